// Round 1
// 3556.136 us; speedup vs baseline: 1.3230x; 1.3230x over previous
//
#include <hip/hip_runtime.h>
#include <stdint.h>

#define H_DIM 4096
#define V_DIM 32000
#define B_DIM 8
#define T_DIM 512
#define M_PER (B_DIM * T_DIM)   // 4096 tokens per model
#define BETA 0.1f
#define IGNORE_IDX (-100)

// ---- 256x256 8-phase GEMM geometry ----
#define BM 256
#define BN 256
#define BKT 64
#define NKT (H_DIM / BKT)        // 64 K-tiles
#define MTILES (M_PER / BM)      // 16
#define NTILES (V_DIM / BN)      // 125
#define TILE_ELEMS (BM * BKT)    // 16384 bf16 elements per staged tile

typedef __attribute__((ext_vector_type(8))) short bf16x8;
typedef __attribute__((ext_vector_type(4))) float f32x4;

#define GAS(p) ((const __attribute__((address_space(1))) void*)(p))
#define LAS(p) ((__attribute__((address_space(3))) void*)(p))

// ---------------- fp32 -> bf16 (RNE) convert, float4-vectorized ----------------
__device__ __forceinline__ unsigned short f32_to_bf16(float f) {
    unsigned int u = __float_as_uint(f);
    u = (u + 0x7FFFu + ((u >> 16) & 1u)) >> 16;
    return (unsigned short)u;
}

__global__ void convert_kernel(const float* __restrict__ src,
                               unsigned short* __restrict__ dst, int n4) {
    int stride = gridDim.x * blockDim.x;
    const float4* s4 = (const float4*)src;
    ushort4* d4 = (ushort4*)dst;
    for (int i = blockIdx.x * blockDim.x + threadIdx.x; i < n4; i += stride) {
        float4 v = s4[i];
        ushort4 o;
        o.x = f32_to_bf16(v.x);
        o.y = f32_to_bf16(v.y);
        o.z = f32_to_bf16(v.z);
        o.w = f32_to_bf16(v.w);
        d4[i] = o;
    }
}

// ---------------- fused 256x256 8-phase GEMM + per-tile softmax partials --------
// grid: x = MTILES*NTILES (2000, XCD-swizzled in-kernel), y = model
__global__ __launch_bounds__(512, 2)
void gemm_lse_kernel(const unsigned short* __restrict__ Xb,  // [2][M_PER][H] bf16
                     const unsigned short* __restrict__ Wb,  // [2][V][H] bf16
                     const long long* __restrict__ y,        // [M_PER]
                     float* __restrict__ pmax,               // [2][NTILES][M_PER]
                     float* __restrict__ psum,               // [2][NTILES][M_PER]
                     float* __restrict__ tgt)                // [2][M_PER]
{
    __shared__ alignas(16) unsigned short As[2][TILE_ELEMS];  // 64 KB
    __shared__ alignas(16) unsigned short Bs[2][TILE_ELEMS];  // 64 KB
    __shared__ float smax[BM][4];                             // 4 KB
    __shared__ float ssum[BM][4];                             // 4 KB
    __shared__ int ylds[BM];                                  // 1 KB

    const int tid = threadIdx.x;
    const int model = blockIdx.y;
    const int bx = blockIdx.x;
    // T1: XCD-aware swizzle; 2000 % 8 == 0 -> simple form is bijective.
    const int swz = (bx & 7) * (MTILES * NTILES / 8) + (bx >> 3);
    const int mt = swz & (MTILES - 1);   // swz % 16
    const int nt = swz >> 4;             // swz / 16 (log2(MTILES)=4)
    const int m0 = mt * BM;
    const int n0 = nt * BN;

    const unsigned short* Abase = Xb + ((size_t)model * M_PER + m0) * H_DIM;
    const unsigned short* Bbase = Wb + ((size_t)model * V_DIM + n0) * H_DIM;

    if (tid < BM) ylds[tid] = (int)y[m0 + tid];   // compiler drains vmcnt here -> clean count

    const int wave = tid >> 6;
    const int lane = tid & 63;
    const int wm = wave >> 2;     // 0..1
    const int wn = wave & 3;      // 0..3
    const int l15 = lane & 15;
    const int quad = lane >> 4;
    const int swz8 = l15 & 7;     // row&7 for all fragment rows (offsets are mult. of 8)

    // staging addresses: thread covers (row = tid>>3) of each 128-row half, slot = tid&7
    // T2 swizzle: LDS stays linear, global SOURCE col is pre-swizzled (rule #21).
    const int srow = tid >> 3;
    const int scol = ((tid & 7) ^ (srow & 7)) * 8;
    const unsigned short* gA = Abase + (size_t)srow * H_DIM + scol;
    const unsigned short* gB = Bbase + (size_t)srow * H_DIM + scol;

    f32x4 acc[8][4];
#pragma unroll
    for (int i = 0; i < 8; ++i)
#pragma unroll
        for (int j = 0; j < 4; ++j) acc[i][j] = {0.f, 0.f, 0.f, 0.f};

    bf16x8 af[4][2], bfr[2][2];

// stage one 128-row half-tile (2 x global_load_lds dwordx4 per thread)
#define STAGE_A(kt, h, bufc) do { \
    const unsigned short* _g = gA + (size_t)(h) * 128 * H_DIM + (size_t)(kt) * BKT; \
    __builtin_amdgcn_global_load_lds(GAS(_g), LAS(As[bufc] + (h) * 8192 + tid * 8), 16, 0, 0); \
    __builtin_amdgcn_global_load_lds(GAS(_g + (size_t)64 * H_DIM), LAS(As[bufc] + (h) * 8192 + 4096 + tid * 8), 16, 0, 0); \
} while (0)
#define STAGE_B(kt, h, bufc) do { \
    const unsigned short* _g = gB + (size_t)(h) * 128 * H_DIM + (size_t)(kt) * BKT; \
    __builtin_amdgcn_global_load_lds(GAS(_g), LAS(Bs[bufc] + (h) * 8192 + tid * 8), 16, 0, 0); \
    __builtin_amdgcn_global_load_lds(GAS(_g + (size_t)64 * H_DIM), LAS(Bs[bufc] + (h) * 8192 + 4096 + tid * 8), 16, 0, 0); \
} while (0)

// fragment reads with the same XOR on the read side (involution)
#define LDA(mh, bufc) { \
    _Pragma("unroll") for (int fl = 0; fl < 4; ++fl) \
    _Pragma("unroll") for (int ks = 0; ks < 2; ++ks) \
        af[fl][ks] = *(const bf16x8*)&As[bufc][(((mh)*4 + fl)*32 + wm*16 + l15)*64 + (((ks*4 + quad) ^ swz8) * 8)]; }
#define LDB(nh, bufc) { \
    _Pragma("unroll") for (int gl = 0; gl < 2; ++gl) \
    _Pragma("unroll") for (int ks = 0; ks < 2; ++ks) \
        bfr[gl][ks] = *(const bf16x8*)&Bs[bufc][(((nh)*2 + gl)*64 + wn*16 + l15)*64 + (((ks*4 + quad) ^ swz8) * 8)]; }

#define MFMAQ(mh, nh) { \
    _Pragma("unroll") for (int fl = 0; fl < 4; ++fl) \
    _Pragma("unroll") for (int gl = 0; gl < 2; ++gl) \
    _Pragma("unroll") for (int ks = 0; ks < 2; ++ks) \
        acc[(mh)*4 + fl][(nh)*2 + gl] = __builtin_amdgcn_mfma_f32_16x16x32_bf16( \
            af[fl][ks], bfr[gl][ks], acc[(mh)*4 + fl][(nh)*2 + gl], 0, 0, 0); }

#define BARR() __builtin_amdgcn_s_barrier()
#define WVM6() asm volatile("s_waitcnt vmcnt(6)" ::: "memory")
#define WVM4() asm volatile("s_waitcnt vmcnt(4)" ::: "memory")
#define WVM0() asm volatile("s_waitcnt vmcnt(0)" ::: "memory")
#define WLG0() asm volatile("s_waitcnt lgkmcnt(0)" ::: "memory")

// One K-tile = 4 phases, Gray order (0,0)->(0,1)->(1,1)->(1,0).
// ph1 stages B-low(kt+1) (other buffer); ph2/3/4 stage A-low/B-high/A-high(kt+2)
// into the regions of THIS buffer that just became dead. Counted vmcnt(6) once
// per tile boundary (vmcnt(0) only when entering the last tile).
#define KTILE(ktv, bufc, obuf) do { \
    LDA(0, bufc); LDB(0, bufc); \
    if ((ktv) + 1 < NKT) { STAGE_B((ktv) + 1, 0, obuf); } \
    BARR(); WLG0(); __builtin_amdgcn_s_setprio(1); MFMAQ(0, 0); __builtin_amdgcn_s_setprio(0); BARR(); \
    LDB(1, bufc); \
    if ((ktv) + 2 < NKT) { STAGE_A((ktv) + 2, 0, bufc); } \
    BARR(); WLG0(); __builtin_amdgcn_s_setprio(1); MFMAQ(0, 1); __builtin_amdgcn_s_setprio(0); BARR(); \
    LDA(1, bufc); \
    if ((ktv) + 2 < NKT) { STAGE_B((ktv) + 2, 1, bufc); } \
    BARR(); WLG0(); __builtin_amdgcn_s_setprio(1); MFMAQ(1, 1); __builtin_amdgcn_s_setprio(0); BARR(); \
    LDB(0, bufc); \
    if ((ktv) + 2 < NKT) { STAGE_A((ktv) + 2, 1, bufc); } \
    BARR(); WLG0(); __builtin_amdgcn_s_setprio(1); MFMAQ(1, 0); __builtin_amdgcn_s_setprio(0); \
    if ((ktv) + 2 == NKT) { WVM0(); } else { WVM6(); } \
    BARR(); \
} while (0)

    // prologue: tile0 fully + 3 halves of tile1; B-low(1) comes in tile0/ph1
    STAGE_A(0, 0, 0); STAGE_B(0, 0, 0); STAGE_B(0, 1, 0); STAGE_A(0, 1, 0);
    WVM4();
    STAGE_A(1, 0, 1); STAGE_B(1, 1, 1); STAGE_A(1, 1, 1);
    WVM6();
    BARR();

    for (int kt = 0; kt < NKT; kt += 2) {
        KTILE(kt, 0, 1);
        KTILE(kt + 1, 1, 0);
    }

    // ---- epilogue: per-row max + sumexp over this 256-col tile; target capture ----
    const size_t mabs = (size_t)model * M_PER + m0;
#pragma unroll
    for (int f = 0; f < 8; ++f) {
#pragma unroll
        for (int r = 0; r < 4; ++r) {
            const int crow = f * 32 + wm * 16 + quad * 4 + r;
            float v0 = acc[f][0][r], v1 = acc[f][1][r], v2 = acc[f][2][r], v3 = acc[f][3][r];
            float mx = fmaxf(fmaxf(v0, v1), fmaxf(v2, v3));
#pragma unroll
            for (int s = 1; s < 16; s <<= 1) mx = fmaxf(mx, __shfl_xor(mx, s));
            float se = __expf(v0 - mx) + __expf(v1 - mx) + __expf(v2 - mx) + __expf(v3 - mx);
#pragma unroll
            for (int s = 1; s < 16; s <<= 1) se += __shfl_xor(se, s);
            if (l15 == 0) { smax[crow][wn] = mx; ssum[crow][wn] = se; }
            int yt = ylds[crow] - n0;   // col = g*64 + wn*16 + l15
            if (yt >= 0 && yt < BN && ((yt >> 4) & 3) == wn && (yt & 15) == l15) {
                int g = yt >> 6;
                float tv = (g == 0) ? v0 : (g == 1) ? v1 : (g == 2) ? v2 : v3;
                tgt[mabs + crow] = tv;
            }
        }
    }
    __syncthreads();
    if (tid < BM) {
        float a0 = smax[tid][0], a1 = smax[tid][1], a2 = smax[tid][2], a3 = smax[tid][3];
        float Mv = fmaxf(fmaxf(a0, a1), fmaxf(a2, a3));
        float Sv = ssum[tid][0] * __expf(a0 - Mv) + ssum[tid][1] * __expf(a1 - Mv)
                 + ssum[tid][2] * __expf(a2 - Mv) + ssum[tid][3] * __expf(a3 - Mv);
        size_t off = ((size_t)model * NTILES + nt) * M_PER + m0 + tid;
        pmax[off] = Mv;
        psum[off] = Sv;
    }
#undef STAGE_A
#undef STAGE_B
#undef LDA
#undef LDB
#undef MFMAQ
#undef KTILE
}

// ---------------- combine partials -> per-sequence (sum logp, count) ----------------
__global__ void combine_kernel(const float* __restrict__ pmax, const float* __restrict__ psum,
                               const float* __restrict__ tgt, const long long* __restrict__ y,
                               float* __restrict__ seqstat /* [2][B][2] */) {
    int b = blockIdx.x;
    int model = blockIdx.y;
    int tid = threadIdx.x;
    float lp = 0.f, cnt = 0.f;
    for (int tt = tid; tt < T_DIM; tt += blockDim.x) {
        int m = b * T_DIM + tt;
        long long yv = y[m];
        if (yv == IGNORE_IDX) continue;
        float gm = -3.4e38f, gs = 0.f;
        for (int nt = 0; nt < NTILES; ++nt) {
            size_t off = ((size_t)model * NTILES + nt) * M_PER + m;
            float pm = pmax[off], ps = psum[off];
            if (pm > gm) { gs = gs * __expf(gm - pm) + ps; gm = pm; }
            else         { gs += ps * __expf(pm - gm); }
        }
        float lse = gm + __logf(gs);
        lp += tgt[(size_t)model * M_PER + m] - lse;
        cnt += 1.f;
    }
#pragma unroll
    for (int s = 32; s; s >>= 1) { lp += __shfl_down(lp, s); cnt += __shfl_down(cnt, s); }
    __shared__ float red[4][2];
    int w = tid >> 6;
    if ((tid & 63) == 0) { red[w][0] = lp; red[w][1] = cnt; }
    __syncthreads();
    if (tid == 0) {
        float sl = 0.f, sc = 0.f;
        for (int i = 0; i < 4; ++i) { sl += red[i][0]; sc += red[i][1]; }
        seqstat[(model * B_DIM + b) * 2 + 0] = sl;
        seqstat[(model * B_DIM + b) * 2 + 1] = sc;
    }
}

// ---------------- final DPO loss ----------------
__global__ void loss_kernel(const float* __restrict__ seqstat, float* __restrict__ out) {
    if (threadIdx.x == 0 && blockIdx.x == 0) {
        float loss = 0.f;
        for (int i = 0; i < B_DIM / 2; ++i) {
            float polc = seqstat[(0 * B_DIM + i) * 2] / fmaxf(seqstat[(0 * B_DIM + i) * 2 + 1], 1.f);
            float refc = seqstat[(1 * B_DIM + i) * 2] / fmaxf(seqstat[(1 * B_DIM + i) * 2 + 1], 1.f);
            float polr = seqstat[(0 * B_DIM + i + 4) * 2] / fmaxf(seqstat[(0 * B_DIM + i + 4) * 2 + 1], 1.f);
            float refr = seqstat[(1 * B_DIM + i + 4) * 2] / fmaxf(seqstat[(1 * B_DIM + i + 4) * 2 + 1], 1.f);
            float d = BETA * ((polc - refc) - (polr - refr));
            float ls = fminf(d, 0.f) - log1pf(__expf(-fabsf(d)));  // log_sigmoid(d), stable
            loss -= ls;
        }
        out[0] = loss / (float)(B_DIM / 2);
    }
}

extern "C" void kernel_launch(void* const* d_in, const int* in_sizes, int n_in,
                              void* d_out, int out_size, void* d_ws, size_t ws_size,
                              hipStream_t stream) {
    const float* x      = (const float*)d_in[0];
    const float* ref_x  = (const float*)d_in[1];
    const long long* y  = (const long long*)d_in[2];
    const float* W      = (const float*)d_in[3];
    const float* ref_W  = (const float*)d_in[4];
    float* out = (float*)d_out;

    // workspace layout (bytes): Xb[2*M*H]*2  Wb[2*V*H]*2  pmax  psum  tgt  seqstat
    char* ws = (char*)d_ws;
    unsigned short* Xb = (unsigned short*)ws;
    unsigned short* Wb = (unsigned short*)(ws + (size_t)2 * M_PER * H_DIM * 2);
    float* pmax = (float*)(ws + (size_t)2 * M_PER * H_DIM * 2 + (size_t)2 * V_DIM * H_DIM * 2);
    float* psum = pmax + (size_t)2 * NTILES * M_PER;
    float* tgt  = psum + (size_t)2 * NTILES * M_PER;
    float* seqstat = tgt + (size_t)2 * M_PER;

    const int nx4 = M_PER * H_DIM / 4;   // 4,194,304
    const int nw4 = V_DIM * H_DIM / 4;   // 32,768,000
    convert_kernel<<<4096, 256, 0, stream>>>(x, Xb, nx4);
    convert_kernel<<<4096, 256, 0, stream>>>(ref_x, Xb + (size_t)M_PER * H_DIM, nx4);
    convert_kernel<<<16384, 256, 0, stream>>>(W, Wb, nw4);
    convert_kernel<<<16384, 256, 0, stream>>>(ref_W, Wb + (size_t)V_DIM * H_DIM, nw4);

    dim3 grid(MTILES * NTILES, 2);   // (2000, 2)
    gemm_lse_kernel<<<grid, 512, 0, stream>>>(Xb, Wb, y, pmax, psum, tgt);

    combine_kernel<<<dim3(B_DIM, 2), 256, 0, stream>>>(pmax, psum, tgt, y, seqstat);
    loss_kernel<<<1, 64, 0, stream>>>(seqstat, out);
}